// Round 7
// baseline (438.835 us; speedup 1.0000x reference)
//
#include <hip/hip_runtime.h>
#include <hip/hip_bf16.h>

// GCNConv + ReLU: out = relu( (A_norm @ (x W)) + b ), A_norm = D^-1/2 (A + I) D^-1/2
// Round 13. Aggregate: ACCEPTED at its concurrency roofline (~13.2M line-gathers
// x ~0.2 lines/cyc/CU ~= 107 us; rounds 4/5/6 traded miss-bytes for overhead and
// never beat round-2's structure). Reverted to round-2 row-major aggregate,
// split into 4 quarter dispatches (~27 us each) for rocprof visibility.
// CSR build REWRITTEN: pass1 (LDS atomics + 6.4MB temp RMW scatter) + pass2
// (re-read + LDS sort) replaced by count (1.6M global atomics into L2-resident
// 200KB) -> 3-stage scan (also emits dinv + cursor) -> fill (atomic cursor,
// 1.6M 2B scattered writes into L2-resident csr16). Arbitrary order within a
// dst list only reorders fp32 adds (harmless). Deletes temp + 1024-thr kernels.

#define FEATS 256

typedef __bf16 bf16x8 __attribute__((ext_vector_type(8)));
typedef float f32x4 __attribute__((ext_vector_type(4)));

__device__ __forceinline__ unsigned short f2bf(float f) {  // RNE
  unsigned u = __float_as_uint(f);
  u += 0x7fffu + ((u >> 16) & 1u);
  return (unsigned short)(u >> 16);
}
__device__ __forceinline__ float bflo(unsigned u) { return __uint_as_float(u << 16); }
__device__ __forceinline__ float bfhi(unsigned u) { return __uint_as_float(u & 0xFFFF0000u); }

// ---------------- CSR build: count -> scan -> fill ----------------

__global__ __launch_bounds__(256) void zero_i32(int* __restrict__ p, int n) {
  int i = blockIdx.x * 256 + threadIdx.x;
  if (i < n) p[i] = 0;
}

__global__ __launch_bounds__(256) void count_deg(const int* __restrict__ dst, int E,
                                                 int* __restrict__ deg) {
  int e = blockIdx.x * 256 + threadIdx.x;
  if (e < E) atomicAdd(&deg[dst[e]], 1);
}

// block-local exclusive scan of deg -> row_ptr; block totals -> bsum; dinv
__global__ __launch_bounds__(256) void scanA(const int* __restrict__ deg,
                                             int* __restrict__ row_ptr,
                                             float* __restrict__ dinv,
                                             int* __restrict__ bsum, int n) {
  __shared__ int tmp[256];
  const int t = threadIdx.x;
  const int i = blockIdx.x * 256 + t;
  const int v = (i < n) ? deg[i] : 0;
  tmp[t] = v;
  __syncthreads();
  #pragma unroll
  for (int off = 1; off < 256; off <<= 1) {
    int x = (t >= off) ? tmp[t - off] : 0;
    __syncthreads();
    tmp[t] += x;
    __syncthreads();
  }
  if (i < n) {
    row_ptr[i] = tmp[t] - v;                 // block-local exclusive
    dinv[i] = rsqrtf((float)(v + 1));        // +1 self loop
  }
  if (t == 255) bsum[blockIdx.x] = tmp[255];
}

// exclusive scan of bsum (nb <= 256), writes row_ptr[n] = grand total
__global__ __launch_bounds__(256) void scanB(int* __restrict__ bsum, int nb,
                                             int* __restrict__ row_ptr, int n) {
  __shared__ int tmp[256];
  const int t = threadIdx.x;
  const int v = (t < nb) ? bsum[t] : 0;
  tmp[t] = v;
  __syncthreads();
  #pragma unroll
  for (int off = 1; off < 256; off <<= 1) {
    int x = (t >= off) ? tmp[t - off] : 0;
    __syncthreads();
    tmp[t] += x;
    __syncthreads();
  }
  if (t < nb) bsum[t] = tmp[t] - v;          // overwrite with exclusive
  if (t == nb - 1) row_ptr[n] = tmp[t];
}

// add block offsets; init cursor = final row_ptr
__global__ __launch_bounds__(256) void scanC(int* __restrict__ row_ptr,
                                             const int* __restrict__ bsum,
                                             int* __restrict__ cursor, int n) {
  const int i = blockIdx.x * 256 + threadIdx.x;
  if (i < n) {
    const int r = row_ptr[i] + bsum[blockIdx.x];
    row_ptr[i] = r;
    cursor[i] = r;
  }
}

// scatter-fill: csr16[pos(dst)] = src  (order within a dst list arbitrary)
__global__ __launch_bounds__(256) void fill_csr(const int* __restrict__ src,
                                                const int* __restrict__ dst, int E,
                                                int* __restrict__ cursor,
                                                unsigned short* __restrict__ csr16) {
  int e = blockIdx.x * 256 + threadIdx.x;
  if (e < E) {
    const int d = dst[e];
    const int s = src[e];
    const int pos = atomicAdd(&cursor[d], 1);
    csr16[pos] = (unsigned short)s;
  }
}

// ---------------- W transpose + bf16 convert: Wt[n][k] = bf16(W[k][n]) ----------------

__global__ __launch_bounds__(256) void wt_build(const float* __restrict__ W,
                                                unsigned short* __restrict__ Wt) {
  int k = blockIdx.x;
  int nn = threadIdx.x;
  Wt[nn * FEATS + k] = f2bf(W[k * FEATS + nn]);
}

// ---------------- MFMA GEMM: xwp[r][:] = bf16( (x @ W)[r][:] * dinv[r] ) ----------------
// Block = 64 rows x 256 cols, 4 waves. Wave wv owns cols [wv*64, wv*64+64):
// B panel (4 ct x 8 kc fragments = 128 VGPRs) loaded once from L2.
// A staged cooperatively: wave wv converts rows [m0+wv*16, +16) fp32->bf16 into
// pre-fragmented LDS (16 B/lane contiguous => conflict-free b128 r/w).

__global__ __launch_bounds__(256, 2) void gemm_mfma(const float* __restrict__ x,
                                                    const unsigned short* __restrict__ Wt,
                                                    const float* __restrict__ dinv,
                                                    unsigned short* __restrict__ xwp, int M) {
  __shared__ bf16x8 A_lds[32 * 64];  // [sub*8+kc][lane], 32 KB
  const int wv   = (int)(threadIdx.x >> 6);
  const int lane = (int)(threadIdx.x & 63);
  const int lm   = lane & 15;
  const int quad = lane >> 4;
  const int m0   = (int)blockIdx.x * 64;

  bf16x8 Bfrag[4][8];
  #pragma unroll
  for (int ct = 0; ct < 4; ++ct) {
    const unsigned short* wrow = Wt + (size_t)(wv * 64 + ct * 16 + lm) * FEATS + quad * 8;
    #pragma unroll
    for (int kc = 0; kc < 8; ++kc)
      Bfrag[ct][kc] = *(const bf16x8*)(wrow + kc * 32);
  }

  {
    int arow = m0 + wv * 16 + lm; if (arow >= M) arow = M - 1;
    const float* xrow = x + (size_t)arow * FEATS + quad * 8;
    #pragma unroll
    for (int kc = 0; kc < 8; ++kc) {
      const float4 f0 = *(const float4*)(xrow + kc * 32);
      const float4 f1 = *(const float4*)(xrow + kc * 32 + 4);
      union { bf16x8 v; unsigned short u[8]; } a;
      a.u[0] = f2bf(f0.x); a.u[1] = f2bf(f0.y); a.u[2] = f2bf(f0.z); a.u[3] = f2bf(f0.w);
      a.u[4] = f2bf(f1.x); a.u[5] = f2bf(f1.y); a.u[6] = f2bf(f1.z); a.u[7] = f2bf(f1.w);
      A_lds[(wv * 8 + kc) * 64 + lane] = a.v;
    }
  }
  __syncthreads();

  #pragma unroll
  for (int sub = 0; sub < 4; ++sub) {
    bf16x8 Af[8];
    #pragma unroll
    for (int kc = 0; kc < 8; ++kc) Af[kc] = A_lds[(sub * 8 + kc) * 64 + lane];

    f32x4 acc[4];
    #pragma unroll
    for (int ct = 0; ct < 4; ++ct) acc[ct] = (f32x4){0.f, 0.f, 0.f, 0.f};

    #pragma unroll
    for (int kc = 0; kc < 8; ++kc) {
      #pragma unroll
      for (int ct = 0; ct < 4; ++ct)
        acc[ct] = __builtin_amdgcn_mfma_f32_16x16x32_bf16(Af[kc], Bfrag[ct][kc], acc[ct], 0, 0, 0);
    }

    #pragma unroll
    for (int r = 0; r < 4; ++r) {
      const int row = m0 + sub * 16 + quad * 4 + r;
      if (row < M) {
        const float dd = dinv[row];
        unsigned short* orow = xwp + (size_t)row * FEATS + wv * 64 + lm;
        #pragma unroll
        for (int ct = 0; ct < 4; ++ct)
          orow[ct * 16] = f2bf(acc[ct][r] * dd);
      }
    }
  }
}

// ---------------- aggregation: one wave per dst node (round-2 structure) ----------------

__global__ __launch_bounds__(256) void aggregate(const unsigned short* __restrict__ xwp,
                                                 const float* __restrict__ dinv,
                                                 const int* __restrict__ row_ptr,
                                                 const unsigned short* __restrict__ csr16,
                                                 const float* __restrict__ bias,
                                                 float* __restrict__ out,
                                                 int n0, int n1) {
  const int node = n0 + (int)((blockIdx.x * blockDim.x + threadIdx.x) >> 6);
  const int lane = (int)(threadIdx.x & 63);
  if (node >= n1) return;
  const int co = lane << 2;

  uint2 sv = *(const uint2*)(xwp + (((size_t)node) << 8) + co);
  float4 acc;
  acc.x = bflo(sv.x); acc.y = bfhi(sv.x); acc.z = bflo(sv.y); acc.w = bfhi(sv.y);

  const int beg = row_ptr[node];
  const int end = row_ptr[node + 1];
  for (int base = beg; base < end; base += 64) {
    int idx = base + lane;
    int s = (idx < end) ? (int)csr16[idx] : 0;
    int m = end - base;
    if (m > 64) m = 64;
    int i = 0;
    for (; i + 8 <= m; i += 8) {
      uint2 v[8];
      #pragma unroll
      for (int j = 0; j < 8; ++j) {
        int sj = __shfl(s, i + j);
        v[j] = *(const uint2*)(xwp + (((size_t)sj) << 8) + co);
      }
      #pragma unroll
      for (int j = 0; j < 8; ++j) {
        acc.x += bflo(v[j].x); acc.y += bfhi(v[j].x);
        acc.z += bflo(v[j].y); acc.w += bfhi(v[j].y);
      }
    }
    for (; i < m; ++i) {
      int sj = __shfl(s, i);
      uint2 v = *(const uint2*)(xwp + (((size_t)sj) << 8) + co);
      acc.x += bflo(v.x); acc.y += bfhi(v.x);
      acc.z += bflo(v.y); acc.w += bfhi(v.y);
    }
  }

  const float dd = dinv[node];
  const float* bp = bias + co;
  f32x4 o;
  o.x = fmaxf(fmaf(acc.x, dd, bp[0]), 0.f);
  o.y = fmaxf(fmaf(acc.y, dd, bp[1]), 0.f);
  o.z = fmaxf(fmaf(acc.z, dd, bp[2]), 0.f);
  o.w = fmaxf(fmaf(acc.w, dd, bp[3]), 0.f);
  // NT store: 51 MB output, written once -- keep xwp in L2
  __builtin_nontemporal_store(o, (f32x4*)(out + (((size_t)node) << 8) + co));
}

// ---------------- launch ----------------

extern "C" void kernel_launch(void* const* d_in, const int* in_sizes, int n_in,
                              void* d_out, int out_size, void* d_ws, size_t ws_size,
                              hipStream_t stream) {
  const float* x  = (const float*)d_in[0];   // [n, 256]
  const int*   ei = (const int*)d_in[1];     // [2, E]
  const float* W  = (const float*)d_in[2];   // [256, 256]
  const float* b  = (const float*)d_in[3];   // [256]

  const int n = in_sizes[0] / FEATS;         // 50000
  const int E = in_sizes[1] / 2;             // 1,600,000
  const int* src = ei;
  const int* dst = ei + E;
  const int nsb = (n + 255) >> 8;            // 196 scan blocks

  // workspace layout (bytes)
  char* ws = (char*)d_ws;
  size_t o0 = 0;
  unsigned short* xwp    = (unsigned short*)(ws + o0); o0 += (size_t)n * 512;  // 25.6 MB
  unsigned short* Wt     = (unsigned short*)(ws + o0); o0 += 131072;
  float*          dinv   = (float*)(ws + o0);          o0 += 200064;
  int*            row_ptr = (int*)(ws + o0);           o0 += 200064;
  int*            deg    = (int*)(ws + o0);            o0 += 200064;
  int*            cursor = (int*)(ws + o0);            o0 += 200064;
  int*            bsum   = (int*)(ws + o0);            o0 += 1024;
  unsigned short* csr16  = (unsigned short*)(ws + o0); o0 += 3200000;
  // total ~29.7 MB

  hipLaunchKernelGGL(zero_i32, dim3(nsb), dim3(256), 0, stream, deg, n);
  hipLaunchKernelGGL(wt_build, dim3(256), dim3(256), 0, stream, W, Wt);

  const int g_e = (E + 255) / 256;  // 6250
  hipLaunchKernelGGL(count_deg, dim3(g_e), dim3(256), 0, stream, dst, E, deg);
  hipLaunchKernelGGL(scanA, dim3(nsb), dim3(256), 0, stream, deg, row_ptr, dinv, bsum, n);
  hipLaunchKernelGGL(scanB, dim3(1), dim3(256), 0, stream, bsum, nsb, row_ptr, n);
  hipLaunchKernelGGL(scanC, dim3(nsb), dim3(256), 0, stream, row_ptr, bsum, cursor, n);
  hipLaunchKernelGGL(fill_csr, dim3(g_e), dim3(256), 0, stream, src, dst, E, cursor, csr16);

  hipLaunchKernelGGL(gemm_mfma, dim3((n + 63) / 64), dim3(256), 0, stream, x, Wt, dinv, xwp, n);

  // aggregate in 4 quarter-range dispatches (~27 us each) for rocprof top-5
  // visibility of the remaining kernels; same total work as one dispatch.
  int qb[5];
  for (int q = 0; q <= 4; ++q) qb[q] = (int)(((long long)n * q) / 4);
  for (int q = 0; q < 4; ++q) {
    const int nn = qb[q + 1] - qb[q];
    hipLaunchKernelGGL(aggregate, dim3((nn * 64 + 255) / 256), dim3(256), 0, stream,
                       xwp, dinv, row_ptr, csr16, b, (float*)d_out, qb[q], qb[q + 1]);
  }
}

// Round 8
// 271.634 us; speedup vs baseline: 1.6155x; 1.6155x over previous
//
#include <hip/hip_runtime.h>
#include <hip/hip_bf16.h>

// GCNConv + ReLU: out = relu( (A_norm @ (x W)) + b ), A_norm = D^-1/2 (A + I) D^-1/2
// Round 14. REVERT round-13's count/scan/fill CSR (fill_csr measured 125 us:
// 35x write amplification from scattered 2B writes + 1.6M dependent device
// atomics) back to the proven LDS-binned pass1/pass2. One structural fix on
// top: buckets narrowed dst>>8 -> dst>>7 (391 buckets x 128 nodes). pass2 LDS
// drops 65->32 KB and grid 196->391 blocks => covers all 256 CUs (~1.5
// blocks/CU vs <1), half the work per block. pass1 keeps identical economics
// (cap 32, same 50KB LDS, spill ~6 sigma). Aggregate = round-2 row-major
// wave-per-node (accepted ~107 us line-request roofline), split into 4
// quarter dispatches (~27 us each) so the next profile exposes every
// remaining kernel >27 us.

#define FEATS 256
#define NBUCK 391     // buckets = dst>>7, 128 nodes each  (50000 -> 391)
#define P1_CAP 32     // LDS slots per bucket per 4096-edge chunk (mean ~10.5)
#define BCAP 5120     // temp capacity per bucket (mean 4096, sigma 64 -> 16 sigma)

typedef __bf16 bf16x8 __attribute__((ext_vector_type(8)));
typedef float f32x4 __attribute__((ext_vector_type(4)));

__device__ __forceinline__ unsigned short f2bf(float f) {  // RNE
  unsigned u = __float_as_uint(f);
  u += 0x7fffu + ((u >> 16) & 1u);
  return (unsigned short)(u >> 16);
}
__device__ __forceinline__ float bflo(unsigned u) { return __uint_as_float(u << 16); }
__device__ __forceinline__ float bfhi(unsigned u) { return __uint_as_float(u & 0xFFFF0000u); }

// ---------------- CSR build ----------------

__global__ __launch_bounds__(256) void zero_i32(int* __restrict__ p, int n) {
  int i = blockIdx.x * 256 + threadIdx.x;
  if (i < n) p[i] = 0;
}

// pass1: bin packed edges (dst<<16|src) by dst>>7. 1024 threads, 4096 edges/block.
__global__ __launch_bounds__(1024) void pass1_bin(const int* __restrict__ src,
                                                  const int* __restrict__ dst,
                                                  int E,
                                                  int* __restrict__ gcursor,
                                                  unsigned* __restrict__ temp) {
  __shared__ unsigned lbuf[NBUCK * P1_CAP];  // 50 KB
  __shared__ int lcnt[NBUCK];
  __shared__ int lbase[NBUCK];
  const int tid = threadIdx.x;
  for (int i = tid; i < NBUCK; i += 1024) lcnt[i] = 0;
  __syncthreads();

  const int e0 = blockIdx.x * 4096;
  #pragma unroll
  for (int i = 0; i < 4; ++i) {
    int e = e0 + i * 1024 + tid;
    if (e < E) {
      unsigned d = (unsigned)dst[e];          // < 65536, fits low 16
      unsigned p = (d << 16) | (unsigned)src[e];
      int b = (int)(d >> 7);
      int pos = atomicAdd(&lcnt[b], 1);
      if (pos < P1_CAP) {
        lbuf[b * P1_CAP + pos] = p;
      } else {  // rare spill (cap ~6 sigma): direct global scatter
        int gp = atomicAdd(&gcursor[b], 1);
        temp[(size_t)b * BCAP + gp] = p;
      }
    }
  }
  __syncthreads();
  if (tid < NBUCK) {
    int c = lcnt[tid]; if (c > P1_CAP) c = P1_CAP;
    lcnt[tid] = c;
    lbase[tid] = atomicAdd(&gcursor[tid], c);
  }
  __syncthreads();
  for (int i = tid; i < NBUCK * P1_CAP; i += 1024) {
    int b = i >> 5, j = i & (P1_CAP - 1);
    if (j < lcnt[b]) temp[(size_t)b * BCAP + lbase[b] + j] = lbuf[i];
  }
}

// exclusive scan over bucket counts (NBUCK <= 512), one block
__global__ __launch_bounds__(512) void scan_buckets(const int* __restrict__ gcursor,
                                                    int* __restrict__ bbase,
                                                    int* __restrict__ row_ptr,
                                                    int n) {
  __shared__ int tmp[512];
  int t = threadIdx.x;
  int v = (t < NBUCK) ? min(gcursor[t], BCAP) : 0;
  tmp[t] = v;
  __syncthreads();
  #pragma unroll
  for (int off = 1; off < 512; off <<= 1) {
    int x = (t >= off) ? tmp[t - off] : 0;
    __syncthreads();
    tmp[t] += x;
    __syncthreads();
  }
  if (t < NBUCK) bbase[t] = tmp[t] - v;
  if (t == 511) row_ptr[n] = tmp[511];
}

// pass2: per-bucket local CSR (128 nodes/bucket). 1024 threads, 32 KB LDS.
__global__ __launch_bounds__(1024) void pass2_csr(const unsigned* __restrict__ temp,
                                                  const int* __restrict__ gcursor,
                                                  const int* __restrict__ bbase,
                                                  unsigned short* __restrict__ csr16,
                                                  int* __restrict__ row_ptr,
                                                  float* __restrict__ dinv, int n) {
  __shared__ unsigned ebuf[BCAP];          // 20 KB
  __shared__ unsigned short sorted[BCAP];  // 10 KB
  __shared__ int hist[128], scn[128], sexcl[128], ofs[128];
  const int b = blockIdx.x;
  const int tid = threadIdx.x;
  int cnt = gcursor[b]; if (cnt > BCAP) cnt = BCAP;
  const int base = bbase[b];
  const unsigned* tp = temp + (size_t)b * BCAP;

  if (tid < 128) { hist[tid] = 0; ofs[tid] = 0; }
  for (int i = tid; i < cnt; i += 1024) ebuf[i] = tp[i];
  __syncthreads();
  for (int i = tid; i < cnt; i += 1024) atomicAdd(&hist[(ebuf[i] >> 16) & 127], 1);
  __syncthreads();

  if (tid < 128) scn[tid] = hist[tid];
  __syncthreads();
  #pragma unroll
  for (int off = 1; off < 128; off <<= 1) {
    int x = 0;
    if (tid < 128 && tid >= off) x = scn[tid - off];
    __syncthreads();
    if (tid < 128) scn[tid] += x;
    __syncthreads();
  }
  if (tid < 128) {
    int v = hist[tid];
    int excl = scn[tid] - v;
    sexcl[tid] = excl;
    int node = (b << 7) + tid;
    if (node < n) {
      row_ptr[node] = base + excl;
      dinv[node] = rsqrtf((float)(v + 1));  // +1 self loop
    }
  }
  __syncthreads();

  for (int i = tid; i < cnt; i += 1024) {
    unsigned e = ebuf[i];
    int dl = (int)((e >> 16) & 127);
    int pos = sexcl[dl] + atomicAdd(&ofs[dl], 1);
    sorted[pos] = (unsigned short)(e & 0xFFFFu);
  }
  __syncthreads();
  for (int i = tid; i < cnt; i += 1024) csr16[base + i] = sorted[i];
}

// ---------------- W transpose + bf16 convert: Wt[n][k] = bf16(W[k][n]) ----------------

__global__ __launch_bounds__(256) void wt_build(const float* __restrict__ W,
                                                unsigned short* __restrict__ Wt) {
  int k = blockIdx.x;
  int nn = threadIdx.x;
  Wt[nn * FEATS + k] = f2bf(W[k * FEATS + nn]);
}

// ---------------- MFMA GEMM: xwp[r][:] = bf16( (x @ W)[r][:] * dinv[r] ) ----------------
// Block = 64 rows x 256 cols, 4 waves; B panel pinned in 128 VGPRs/wave,
// A converted cooperatively into pre-fragmented LDS (conflict-free b128 r/w).

__global__ __launch_bounds__(256, 2) void gemm_mfma(const float* __restrict__ x,
                                                    const unsigned short* __restrict__ Wt,
                                                    const float* __restrict__ dinv,
                                                    unsigned short* __restrict__ xwp, int M) {
  __shared__ bf16x8 A_lds[32 * 64];  // [sub*8+kc][lane], 32 KB
  const int wv   = (int)(threadIdx.x >> 6);
  const int lane = (int)(threadIdx.x & 63);
  const int lm   = lane & 15;
  const int quad = lane >> 4;
  const int m0   = (int)blockIdx.x * 64;

  bf16x8 Bfrag[4][8];
  #pragma unroll
  for (int ct = 0; ct < 4; ++ct) {
    const unsigned short* wrow = Wt + (size_t)(wv * 64 + ct * 16 + lm) * FEATS + quad * 8;
    #pragma unroll
    for (int kc = 0; kc < 8; ++kc)
      Bfrag[ct][kc] = *(const bf16x8*)(wrow + kc * 32);
  }

  {
    int arow = m0 + wv * 16 + lm; if (arow >= M) arow = M - 1;
    const float* xrow = x + (size_t)arow * FEATS + quad * 8;
    #pragma unroll
    for (int kc = 0; kc < 8; ++kc) {
      const float4 f0 = *(const float4*)(xrow + kc * 32);
      const float4 f1 = *(const float4*)(xrow + kc * 32 + 4);
      union { bf16x8 v; unsigned short u[8]; } a;
      a.u[0] = f2bf(f0.x); a.u[1] = f2bf(f0.y); a.u[2] = f2bf(f0.z); a.u[3] = f2bf(f0.w);
      a.u[4] = f2bf(f1.x); a.u[5] = f2bf(f1.y); a.u[6] = f2bf(f1.z); a.u[7] = f2bf(f1.w);
      A_lds[(wv * 8 + kc) * 64 + lane] = a.v;
    }
  }
  __syncthreads();

  #pragma unroll
  for (int sub = 0; sub < 4; ++sub) {
    bf16x8 Af[8];
    #pragma unroll
    for (int kc = 0; kc < 8; ++kc) Af[kc] = A_lds[(sub * 8 + kc) * 64 + lane];

    f32x4 acc[4];
    #pragma unroll
    for (int ct = 0; ct < 4; ++ct) acc[ct] = (f32x4){0.f, 0.f, 0.f, 0.f};

    #pragma unroll
    for (int kc = 0; kc < 8; ++kc) {
      #pragma unroll
      for (int ct = 0; ct < 4; ++ct)
        acc[ct] = __builtin_amdgcn_mfma_f32_16x16x32_bf16(Af[kc], Bfrag[ct][kc], acc[ct], 0, 0, 0);
    }

    #pragma unroll
    for (int r = 0; r < 4; ++r) {
      const int row = m0 + sub * 16 + quad * 4 + r;
      if (row < M) {
        const float dd = dinv[row];
        unsigned short* orow = xwp + (size_t)row * FEATS + wv * 64 + lm;
        #pragma unroll
        for (int ct = 0; ct < 4; ++ct)
          orow[ct * 16] = f2bf(acc[ct][r] * dd);
      }
    }
  }
}

// ---------------- aggregation: one wave per dst node (round-2 structure) ----------------
// ACCEPTED at its line-request roofline: ~13.2M 64B-line gathers at ~0.2
// lines/cyc/CU ~= 107 us total; slicing/packing variants (rounds 9-12) traded
// miss-bytes for overhead and never beat this. 4-way split for profiling only.

__global__ __launch_bounds__(256) void aggregate(const unsigned short* __restrict__ xwp,
                                                 const float* __restrict__ dinv,
                                                 const int* __restrict__ row_ptr,
                                                 const unsigned short* __restrict__ csr16,
                                                 const float* __restrict__ bias,
                                                 float* __restrict__ out,
                                                 int n0, int n1) {
  const int node = n0 + (int)((blockIdx.x * blockDim.x + threadIdx.x) >> 6);
  const int lane = (int)(threadIdx.x & 63);
  if (node >= n1) return;
  const int co = lane << 2;

  uint2 sv = *(const uint2*)(xwp + (((size_t)node) << 8) + co);
  float4 acc;
  acc.x = bflo(sv.x); acc.y = bfhi(sv.x); acc.z = bflo(sv.y); acc.w = bfhi(sv.y);

  const int beg = row_ptr[node];
  const int end = row_ptr[node + 1];
  for (int base = beg; base < end; base += 64) {
    int idx = base + lane;
    int s = (idx < end) ? (int)csr16[idx] : 0;
    int m = end - base;
    if (m > 64) m = 64;
    int i = 0;
    for (; i + 8 <= m; i += 8) {
      uint2 v[8];
      #pragma unroll
      for (int j = 0; j < 8; ++j) {
        int sj = __shfl(s, i + j);
        v[j] = *(const uint2*)(xwp + (((size_t)sj) << 8) + co);
      }
      #pragma unroll
      for (int j = 0; j < 8; ++j) {
        acc.x += bflo(v[j].x); acc.y += bfhi(v[j].x);
        acc.z += bflo(v[j].y); acc.w += bfhi(v[j].y);
      }
    }
    for (; i < m; ++i) {
      int sj = __shfl(s, i);
      uint2 v = *(const uint2*)(xwp + (((size_t)sj) << 8) + co);
      acc.x += bflo(v.x); acc.y += bfhi(v.x);
      acc.z += bflo(v.y); acc.w += bfhi(v.y);
    }
  }

  const float dd = dinv[node];
  const float* bp = bias + co;
  f32x4 o;
  o.x = fmaxf(fmaf(acc.x, dd, bp[0]), 0.f);
  o.y = fmaxf(fmaf(acc.y, dd, bp[1]), 0.f);
  o.z = fmaxf(fmaf(acc.z, dd, bp[2]), 0.f);
  o.w = fmaxf(fmaf(acc.w, dd, bp[3]), 0.f);
  // NT store: 51 MB output, written once -- keep xwp in L2
  __builtin_nontemporal_store(o, (f32x4*)(out + (((size_t)node) << 8) + co));
}

// ---------------- launch ----------------

extern "C" void kernel_launch(void* const* d_in, const int* in_sizes, int n_in,
                              void* d_out, int out_size, void* d_ws, size_t ws_size,
                              hipStream_t stream) {
  const float* x  = (const float*)d_in[0];   // [n, 256]
  const int*   ei = (const int*)d_in[1];     // [2, E]
  const float* W  = (const float*)d_in[2];   // [256, 256]
  const float* b  = (const float*)d_in[3];   // [256]

  const int n = in_sizes[0] / FEATS;         // 50000
  const int E = in_sizes[1] / 2;             // 1,600,000
  const int* src = ei;
  const int* dst = ei + E;

  // workspace layout (bytes)
  char* ws = (char*)d_ws;
  size_t o0 = 0;
  unsigned short* xwp    = (unsigned short*)(ws + o0); o0 += (size_t)n * 512;  // 25.6 MB
  unsigned short* Wt     = (unsigned short*)(ws + o0); o0 += 131072;
  float*          dinv   = (float*)(ws + o0);          o0 += 200064;
  int*            row_ptr = (int*)(ws + o0);           o0 += 200064;
  unsigned short* csr16  = (unsigned short*)(ws + o0); o0 += 3200000;
  int*            gcursor = (int*)(ws + o0);           o0 += 2048;
  int*            bbase   = (int*)(ws + o0);           o0 += 2048;
  unsigned*       temp    = (unsigned*)(ws + o0);      o0 += (size_t)NBUCK * BCAP * 4;
  // total ~37.4 MB

  hipLaunchKernelGGL(zero_i32, dim3(2), dim3(256), 0, stream, gcursor, NBUCK);
  hipLaunchKernelGGL(wt_build, dim3(256), dim3(256), 0, stream, W, Wt);

  const int g_p1 = (E + 4095) / 4096;  // 391
  hipLaunchKernelGGL(pass1_bin, dim3(g_p1), dim3(1024), 0, stream, src, dst, E, gcursor, temp);
  hipLaunchKernelGGL(scan_buckets, dim3(1), dim3(512), 0, stream, gcursor, bbase, row_ptr, n);
  hipLaunchKernelGGL(pass2_csr, dim3(NBUCK), dim3(1024), 0, stream, temp, gcursor, bbase,
                     csr16, row_ptr, dinv, n);

  hipLaunchKernelGGL(gemm_mfma, dim3((n + 63) / 64), dim3(256), 0, stream, x, Wt, dinv, xwp, n);

  // aggregate in 4 quarter-range dispatches (~27 us each): same total work,
  // lowers the rocprof top-5 cutoff so every kernel >27 us is visible.
  int qb[5];
  for (int q = 0; q <= 4; ++q) qb[q] = (int)(((long long)n * q) / 4);
  for (int q = 0; q < 4; ++q) {
    const int nn = qb[q + 1] - qb[q];
    hipLaunchKernelGGL(aggregate, dim3((nn * 64 + 255) / 256), dim3(256), 0, stream,
                       xwp, dinv, row_ptr, csr16, b, (float*)d_out, qb[q], qb[q + 1]);
  }
}

// Round 9
// 258.605 us; speedup vs baseline: 1.6969x; 1.0504x over previous
//
#include <hip/hip_runtime.h>
#include <hip/hip_bf16.h>

// GCNConv + ReLU: out = relu( (A_norm @ (x W)) + b ), A_norm = D^-1/2 (A + I) D^-1/2
// Round 15. (1) gemm epilogue fix: round-8 profile showed gemm=41us at
// MfmaUtil 5.4% / VALU 6.4% -- bound by 64 scalar 2B global stores per wave
// (each scatters 16x32B segments => ~3.2M L2 transactions). Now stages C in a
// 32KB LDS tile (cols XOR-swizzled by quad so ds_write_b16 is conflict-free)
// and writes coalesced 512B rows (8 dwordx4/thread). (2) CSR build reverted to
// the proven 196-bucket pass1/pass2 (round-14's 391-bucket variant + 4-way agg
// split cost ~15us). (3) aggregate (accepted ~107us line-request roofline)
// split in 2 halves (~53us each) -- outranks the harness's 41us fillBuffer
// dispatches in rocprof top-5, restoring per-kernel visibility.

#define FEATS 256
#define MAXBUCK 200   // >= (50000+255)>>8 = 196
#define P1_CAP 64     // LDS slots per bucket per 4096-edge chunk (mean ~21)
#define BCAP 10240    // temp capacity per bucket (mean 8192, ~22 sigma)

typedef __bf16 bf16x8 __attribute__((ext_vector_type(8)));
typedef float f32x4 __attribute__((ext_vector_type(4)));

__device__ __forceinline__ unsigned short f2bf(float f) {  // RNE
  unsigned u = __float_as_uint(f);
  u += 0x7fffu + ((u >> 16) & 1u);
  return (unsigned short)(u >> 16);
}
__device__ __forceinline__ float bflo(unsigned u) { return __uint_as_float(u << 16); }
__device__ __forceinline__ float bfhi(unsigned u) { return __uint_as_float(u & 0xFFFF0000u); }

// ---------------- CSR build ----------------

__global__ __launch_bounds__(256) void zero_i32(int* __restrict__ p, int n) {
  int i = blockIdx.x * 256 + threadIdx.x;
  if (i < n) p[i] = 0;
}

// pass1: bin packed edges (dst<<16|src) by dst>>8. 1024 threads, 4096 edges/block.
__global__ __launch_bounds__(1024) void pass1_bin(const int* __restrict__ src,
                                                  const int* __restrict__ dst,
                                                  int E, int nbuck,
                                                  int* __restrict__ gcursor,
                                                  unsigned* __restrict__ temp) {
  __shared__ unsigned lbuf[MAXBUCK * P1_CAP];  // 51.2 KB
  __shared__ int lcnt[MAXBUCK];
  __shared__ int lbase[MAXBUCK];
  const int tid = threadIdx.x;
  for (int i = tid; i < nbuck; i += 1024) lcnt[i] = 0;
  __syncthreads();

  const int e0 = blockIdx.x * 4096;
  #pragma unroll
  for (int i = 0; i < 4; ++i) {
    int e = e0 + i * 1024 + tid;
    if (e < E) {
      unsigned d = (unsigned)dst[e];
      unsigned p = (d << 16) | (unsigned)src[e];
      int b = (int)(d >> 8);
      int pos = atomicAdd(&lcnt[b], 1);
      if (pos < P1_CAP) {
        lbuf[b * P1_CAP + pos] = p;
      } else {  // rare spill: direct global scatter
        int gp = atomicAdd(&gcursor[b], 1);
        temp[(size_t)b * BCAP + gp] = p;
      }
    }
  }
  __syncthreads();
  if (tid < nbuck) {
    int c = lcnt[tid]; if (c > P1_CAP) c = P1_CAP;
    lcnt[tid] = c;
    lbase[tid] = atomicAdd(&gcursor[tid], c);
  }
  __syncthreads();
  for (int i = tid; i < nbuck * P1_CAP; i += 1024) {
    int b = i >> 6, j = i & (P1_CAP - 1);
    if (j < lcnt[b]) temp[(size_t)b * BCAP + lbase[b] + j] = lbuf[i];
  }
}

// exclusive scan over bucket counts (nbuck <= 256), one block
__global__ __launch_bounds__(256) void scan_buckets(const int* __restrict__ gcursor,
                                                    int* __restrict__ bbase,
                                                    int* __restrict__ row_ptr,
                                                    int nbuck, int n) {
  __shared__ int tmp[256];
  int t = threadIdx.x;
  int v = (t < nbuck) ? min(gcursor[t], BCAP) : 0;
  tmp[t] = v;
  __syncthreads();
  #pragma unroll
  for (int off = 1; off < 256; off <<= 1) {
    int x = (t >= off) ? tmp[t - off] : 0;
    __syncthreads();
    tmp[t] += x;
    __syncthreads();
  }
  if (t < nbuck) bbase[t] = tmp[t] - v;
  if (t == 0) row_ptr[n] = tmp[255];
}

// pass2: per-bucket local CSR. 1024 threads.
__global__ __launch_bounds__(1024) void pass2_csr(const unsigned* __restrict__ temp,
                                                  const int* __restrict__ gcursor,
                                                  const int* __restrict__ bbase,
                                                  unsigned short* __restrict__ csr16,
                                                  int* __restrict__ row_ptr,
                                                  float* __restrict__ dinv, int n) {
  __shared__ unsigned ebuf[BCAP];          // 40 KB
  __shared__ unsigned short sorted[BCAP];  // 20 KB
  __shared__ int hist[256], scn[256], sexcl[256], ofs[256];
  const int b = blockIdx.x;
  const int tid = threadIdx.x;
  int cnt = gcursor[b]; if (cnt > BCAP) cnt = BCAP;
  const int base = bbase[b];
  const unsigned* tp = temp + (size_t)b * BCAP;

  if (tid < 256) { hist[tid] = 0; ofs[tid] = 0; }
  for (int i = tid; i < cnt; i += 1024) ebuf[i] = tp[i];
  __syncthreads();
  for (int i = tid; i < cnt; i += 1024) atomicAdd(&hist[(ebuf[i] >> 16) & 255], 1);
  __syncthreads();

  if (tid < 256) scn[tid] = hist[tid];
  __syncthreads();
  #pragma unroll
  for (int off = 1; off < 256; off <<= 1) {
    int x = 0;
    if (tid < 256 && tid >= off) x = scn[tid - off];
    __syncthreads();
    if (tid < 256) scn[tid] += x;
    __syncthreads();
  }
  if (tid < 256) {
    int v = hist[tid];
    int excl = scn[tid] - v;
    sexcl[tid] = excl;
    int node = (b << 8) + tid;
    if (node < n) {
      row_ptr[node] = base + excl;
      dinv[node] = rsqrtf((float)(v + 1));  // +1 self loop
    }
  }
  __syncthreads();

  for (int i = tid; i < cnt; i += 1024) {
    unsigned e = ebuf[i];
    int dl = (int)((e >> 16) & 255);
    int pos = sexcl[dl] + atomicAdd(&ofs[dl], 1);
    sorted[pos] = (unsigned short)(e & 0xFFFFu);
  }
  __syncthreads();
  for (int i = tid; i < cnt; i += 1024) csr16[base + i] = sorted[i];
}

// ---------------- W transpose + bf16 convert: Wt[n][k] = bf16(W[k][n]) ----------------

__global__ __launch_bounds__(256) void wt_build(const float* __restrict__ W,
                                                unsigned short* __restrict__ Wt) {
  int k = blockIdx.x;
  int nn = threadIdx.x;
  Wt[nn * FEATS + k] = f2bf(W[k * FEATS + nn]);
}

// ---------------- MFMA GEMM: xwp[r][:] = bf16( (x @ W)[r][:] * dinv[r] ) ----------------
// Block = 64 rows x 256 cols, 4 waves; B panel pinned in 128 VGPRs/wave; A
// converted cooperatively into pre-fragmented LDS. NEW epilogue: C staged in a
// 32 KB LDS tile -- store col group XOR-swizzled by quad ((ct^quad) field) so
// each ds_write_b16 hits 4 distinct 8-bank groups (2 lanes/bank = free), then
// 8 rounds of coalesced 512 B row writes (dwordx4) replace 64 scalar global
// stores/wave (the round-8 bottleneck: ~3.2M 32B L2 segment transactions).

__global__ __launch_bounds__(256, 2) void gemm_mfma(const float* __restrict__ x,
                                                    const unsigned short* __restrict__ Wt,
                                                    const float* __restrict__ dinv,
                                                    unsigned short* __restrict__ xwp, int M) {
  __shared__ bf16x8 A_lds[32 * 64];            // 32 KB: [sub*8+kc][lane]
  __shared__ unsigned short C_lds[64 * 256];   // 32 KB: [row][swizzled col]
  const int wv   = (int)(threadIdx.x >> 6);
  const int lane = (int)(threadIdx.x & 63);
  const int lm   = lane & 15;
  const int quad = lane >> 4;
  const int m0   = (int)blockIdx.x * 64;

  bf16x8 Bfrag[4][8];
  #pragma unroll
  for (int ct = 0; ct < 4; ++ct) {
    const unsigned short* wrow = Wt + (size_t)(wv * 64 + ct * 16 + lm) * FEATS + quad * 8;
    #pragma unroll
    for (int kc = 0; kc < 8; ++kc)
      Bfrag[ct][kc] = *(const bf16x8*)(wrow + kc * 32);
  }

  {
    int arow = m0 + wv * 16 + lm; if (arow >= M) arow = M - 1;
    const float* xrow = x + (size_t)arow * FEATS + quad * 8;
    #pragma unroll
    for (int kc = 0; kc < 8; ++kc) {
      const float4 f0 = *(const float4*)(xrow + kc * 32);
      const float4 f1 = *(const float4*)(xrow + kc * 32 + 4);
      union { bf16x8 v; unsigned short u[8]; } a;
      a.u[0] = f2bf(f0.x); a.u[1] = f2bf(f0.y); a.u[2] = f2bf(f0.z); a.u[3] = f2bf(f0.w);
      a.u[4] = f2bf(f1.x); a.u[5] = f2bf(f1.y); a.u[6] = f2bf(f1.z); a.u[7] = f2bf(f1.w);
      A_lds[(wv * 8 + kc) * 64 + lane] = a.v;
    }
  }
  __syncthreads();

  #pragma unroll
  for (int sub = 0; sub < 4; ++sub) {
    bf16x8 Af[8];
    #pragma unroll
    for (int kc = 0; kc < 8; ++kc) Af[kc] = A_lds[(sub * 8 + kc) * 64 + lane];

    f32x4 acc[4];
    #pragma unroll
    for (int ct = 0; ct < 4; ++ct) acc[ct] = (f32x4){0.f, 0.f, 0.f, 0.f};

    #pragma unroll
    for (int kc = 0; kc < 8; ++kc) {
      #pragma unroll
      for (int ct = 0; ct < 4; ++ct)
        acc[ct] = __builtin_amdgcn_mfma_f32_16x16x32_bf16(Af[kc], Bfrag[ct][kc], acc[ct], 0, 0, 0);
    }

    #pragma unroll
    for (int r = 0; r < 4; ++r) {
      const int lrow = sub * 16 + quad * 4 + r;
      int grow = m0 + lrow; if (grow >= M) grow = M - 1;
      const float dd = dinv[grow];
      #pragma unroll
      for (int ct = 0; ct < 4; ++ct)
        C_lds[lrow * 256 + wv * 64 + ((ct ^ quad) << 4) + lm] = f2bf(acc[ct][r] * dd);
    }
  }
  __syncthreads();

  // coalesced writeout: 8 rounds x 8 rows; 32 threads/row x 16 B = 512 B/row.
  // Un-swizzle: stored col = col ^ (quad_of_row << 4)  (bytes: ^ quad<<5).
  const int t  = (int)(threadIdx.x & 31);
  const int r8 = (int)(threadIdx.x >> 5);  // 0..7
  #pragma unroll
  for (int j = 0; j < 8; ++j) {
    const int lrow = j * 8 + r8;
    const int grow = m0 + lrow;
    if (grow < M) {
      const int qr = (lrow >> 2) & 3;
      const unsigned short* srcp = C_lds + lrow * 256 + (((t * 16) ^ (qr << 5)) >> 1);
      *(uint4*)(xwp + (size_t)grow * FEATS + t * 8) = *(const uint4*)srcp;
    }
  }
}

// ---------------- aggregation: one wave per dst node (round-2 structure) ----------------
// ACCEPTED at its line-request roofline: ~13.2M 64B-line gathers at ~0.2
// lines/cyc/CU ~= 107 us total; slicing/packing variants (rounds 9-12) traded
// miss-bytes for overhead and never beat this. 2-way split for profiling only.

__global__ __launch_bounds__(256) void aggregate(const unsigned short* __restrict__ xwp,
                                                 const float* __restrict__ dinv,
                                                 const int* __restrict__ row_ptr,
                                                 const unsigned short* __restrict__ csr16,
                                                 const float* __restrict__ bias,
                                                 float* __restrict__ out,
                                                 int n0, int n1) {
  const int node = n0 + (int)((blockIdx.x * blockDim.x + threadIdx.x) >> 6);
  const int lane = (int)(threadIdx.x & 63);
  if (node >= n1) return;
  const int co = lane << 2;

  uint2 sv = *(const uint2*)(xwp + (((size_t)node) << 8) + co);
  float4 acc;
  acc.x = bflo(sv.x); acc.y = bfhi(sv.x); acc.z = bflo(sv.y); acc.w = bfhi(sv.y);

  const int beg = row_ptr[node];
  const int end = row_ptr[node + 1];
  for (int base = beg; base < end; base += 64) {
    int idx = base + lane;
    int s = (idx < end) ? (int)csr16[idx] : 0;
    int m = end - base;
    if (m > 64) m = 64;
    int i = 0;
    for (; i + 8 <= m; i += 8) {
      uint2 v[8];
      #pragma unroll
      for (int j = 0; j < 8; ++j) {
        int sj = __shfl(s, i + j);
        v[j] = *(const uint2*)(xwp + (((size_t)sj) << 8) + co);
      }
      #pragma unroll
      for (int j = 0; j < 8; ++j) {
        acc.x += bflo(v[j].x); acc.y += bfhi(v[j].x);
        acc.z += bflo(v[j].y); acc.w += bfhi(v[j].y);
      }
    }
    for (; i < m; ++i) {
      int sj = __shfl(s, i);
      uint2 v = *(const uint2*)(xwp + (((size_t)sj) << 8) + co);
      acc.x += bflo(v.x); acc.y += bfhi(v.x);
      acc.z += bflo(v.y); acc.w += bfhi(v.y);
    }
  }

  const float dd = dinv[node];
  const float* bp = bias + co;
  f32x4 o;
  o.x = fmaxf(fmaf(acc.x, dd, bp[0]), 0.f);
  o.y = fmaxf(fmaf(acc.y, dd, bp[1]), 0.f);
  o.z = fmaxf(fmaf(acc.z, dd, bp[2]), 0.f);
  o.w = fmaxf(fmaf(acc.w, dd, bp[3]), 0.f);
  // NT store: 51 MB output, written once -- keep xwp in L2
  __builtin_nontemporal_store(o, (f32x4*)(out + (((size_t)node) << 8) + co));
}

// ---------------- launch ----------------

extern "C" void kernel_launch(void* const* d_in, const int* in_sizes, int n_in,
                              void* d_out, int out_size, void* d_ws, size_t ws_size,
                              hipStream_t stream) {
  const float* x  = (const float*)d_in[0];   // [n, 256]
  const int*   ei = (const int*)d_in[1];     // [2, E]
  const float* W  = (const float*)d_in[2];   // [256, 256]
  const float* b  = (const float*)d_in[3];   // [256]

  const int n = in_sizes[0] / FEATS;         // 50000
  const int E = in_sizes[1] / 2;             // 1,600,000
  const int* src = ei;
  const int* dst = ei + E;
  const int nbuck = (n + 255) >> 8;          // 196

  // workspace layout (bytes)
  char* ws = (char*)d_ws;
  size_t o0 = 0;
  unsigned short* xwp    = (unsigned short*)(ws + o0); o0 += (size_t)n * 512;  // 25.6 MB
  unsigned short* Wt     = (unsigned short*)(ws + o0); o0 += 131072;
  float*          dinv   = (float*)(ws + o0);          o0 += 200064;
  int*            row_ptr = (int*)(ws + o0);           o0 += 200064;
  unsigned short* csr16  = (unsigned short*)(ws + o0); o0 += 3200000;
  int*            gcursor = (int*)(ws + o0);           o0 += 1024;
  int*            bbase   = (int*)(ws + o0);           o0 += 1024;
  unsigned*       temp    = (unsigned*)(ws + o0);      o0 += (size_t)MAXBUCK * BCAP * 4;
  // total ~37.4 MB

  hipLaunchKernelGGL(zero_i32, dim3(1), dim3(256), 0, stream, gcursor, nbuck);
  hipLaunchKernelGGL(wt_build, dim3(256), dim3(256), 0, stream, W, Wt);

  const int g_p1 = (E + 4095) / 4096;  // 391
  hipLaunchKernelGGL(pass1_bin, dim3(g_p1), dim3(1024), 0, stream, src, dst, E, nbuck, gcursor, temp);
  hipLaunchKernelGGL(scan_buckets, dim3(1), dim3(256), 0, stream, gcursor, bbase, row_ptr, nbuck, n);
  hipLaunchKernelGGL(pass2_csr, dim3(nbuck), dim3(1024), 0, stream, temp, gcursor, bbase,
                     csr16, row_ptr, dinv, n);

  hipLaunchKernelGGL(gemm_mfma, dim3((n + 63) / 64), dim3(256), 0, stream, x, Wt, dinv, xwp, n);

  // aggregate in 2 half-range dispatches (~53 us each): outranks the harness's
  // ~41 us fillBuffer dispatches in rocprof top-5; minimal launch overhead.
  const int nh = (n + 1) >> 1;
  const int g_agg = (nh * 64 + 255) / 256;
  hipLaunchKernelGGL(aggregate, dim3(g_agg), dim3(256), 0, stream,
                     xwp, dinv, row_ptr, csr16, b, (float*)d_out, 0, nh);
  hipLaunchKernelGGL(aggregate, dim3(g_agg), dim3(256), 0, stream,
                     xwp, dinv, row_ptr, csr16, b, (float*)d_out, nh, n);
}

// Round 11
// 251.929 us; speedup vs baseline: 1.7419x; 1.0265x over previous
//
#include <hip/hip_runtime.h>
#include <hip/hip_bf16.h>

// GCNConv + ReLU: out = relu( (A_norm @ (x W)) + b ), A_norm = D^-1/2 (A + I) D^-1/2
// Round 17: RESUBMIT of round-16 (container failed twice; source audit found no
// OOB/hang path; identical infra signature as round 3's false failure, which
// passed verbatim on resubmit). Change under test: aggregate = paired-edge
// uint4 gathers. Causality evidence: round 2 (1.65M gather instrs, 3.35 TB/s
// miss-BW) and round 5 (same instrs, 1.65 TB/s) both ~107-115 us => limiter is
// per-CU gather-INSTRUCTION throughput (~39 cyc/instr), not fetch bytes. Wave
// = 2 edges x 32 lanes x uint4: one instr moves TWO 512 B rows; instr count
// 1.65M -> ~0.9M. 8 acc/lane, shfl_xor(32) fold, sentinel row n absorbs tails,
// 4-gather short-tail round limits sentinel waste. Single agg dispatch;
// zero+sentinel init fused into wt_init. CSR: proven 196-bucket pass1/pass2.
// GEMM: round-15 LDS epilogue (passed at 258.6 us).

#define FEATS 256
#define MAXBUCK 200   // >= (50000+255)>>8 = 196
#define P1_CAP 64     // LDS slots per bucket per 4096-edge chunk (mean ~21)
#define BCAP 10240    // temp capacity per bucket (mean 8192, ~22 sigma)

typedef __bf16 bf16x8 __attribute__((ext_vector_type(8)));
typedef float f32x4 __attribute__((ext_vector_type(4)));

__device__ __forceinline__ unsigned short f2bf(float f) {  // RNE
  unsigned u = __float_as_uint(f);
  u += 0x7fffu + ((u >> 16) & 1u);
  return (unsigned short)(u >> 16);
}
__device__ __forceinline__ float bflo(unsigned u) { return __uint_as_float(u << 16); }
__device__ __forceinline__ float bfhi(unsigned u) { return __uint_as_float(u & 0xFFFF0000u); }

// ---------------- CSR build ----------------

// pass1: bin packed edges (dst<<16|src) by dst>>8. 1024 threads, 4096 edges/block.
__global__ __launch_bounds__(1024) void pass1_bin(const int* __restrict__ src,
                                                  const int* __restrict__ dst,
                                                  int E, int nbuck,
                                                  int* __restrict__ gcursor,
                                                  unsigned* __restrict__ temp) {
  __shared__ unsigned lbuf[MAXBUCK * P1_CAP];  // 51.2 KB
  __shared__ int lcnt[MAXBUCK];
  __shared__ int lbase[MAXBUCK];
  const int tid = threadIdx.x;
  for (int i = tid; i < nbuck; i += 1024) lcnt[i] = 0;
  __syncthreads();

  const int e0 = blockIdx.x * 4096;
  #pragma unroll
  for (int i = 0; i < 4; ++i) {
    int e = e0 + i * 1024 + tid;
    if (e < E) {
      unsigned d = (unsigned)dst[e];
      unsigned p = (d << 16) | (unsigned)src[e];
      int b = (int)(d >> 8);
      int pos = atomicAdd(&lcnt[b], 1);
      if (pos < P1_CAP) {
        lbuf[b * P1_CAP + pos] = p;
      } else {  // rare spill: direct global scatter
        int gp = atomicAdd(&gcursor[b], 1);
        temp[(size_t)b * BCAP + gp] = p;
      }
    }
  }
  __syncthreads();
  if (tid < nbuck) {
    int c = lcnt[tid]; if (c > P1_CAP) c = P1_CAP;
    lcnt[tid] = c;
    lbase[tid] = atomicAdd(&gcursor[tid], c);
  }
  __syncthreads();
  for (int i = tid; i < nbuck * P1_CAP; i += 1024) {
    int b = i >> 6, j = i & (P1_CAP - 1);
    if (j < lcnt[b]) temp[(size_t)b * BCAP + lbase[b] + j] = lbuf[i];
  }
}

// exclusive scan over bucket counts (nbuck <= 256), one block
__global__ __launch_bounds__(256) void scan_buckets(const int* __restrict__ gcursor,
                                                    int* __restrict__ bbase,
                                                    int* __restrict__ row_ptr,
                                                    int nbuck, int n) {
  __shared__ int tmp[256];
  int t = threadIdx.x;
  int v = (t < nbuck) ? min(gcursor[t], BCAP) : 0;
  tmp[t] = v;
  __syncthreads();
  #pragma unroll
  for (int off = 1; off < 256; off <<= 1) {
    int x = (t >= off) ? tmp[t - off] : 0;
    __syncthreads();
    tmp[t] += x;
    __syncthreads();
  }
  if (t < nbuck) bbase[t] = tmp[t] - v;
  if (t == 0) row_ptr[n] = tmp[255];
}

// pass2: per-bucket local CSR. 1024 threads.
__global__ __launch_bounds__(1024) void pass2_csr(const unsigned* __restrict__ temp,
                                                  const int* __restrict__ gcursor,
                                                  const int* __restrict__ bbase,
                                                  unsigned short* __restrict__ csr16,
                                                  int* __restrict__ row_ptr,
                                                  float* __restrict__ dinv, int n) {
  __shared__ unsigned ebuf[BCAP];          // 40 KB
  __shared__ unsigned short sorted[BCAP];  // 20 KB
  __shared__ int hist[256], scn[256], sexcl[256], ofs[256];
  const int b = blockIdx.x;
  const int tid = threadIdx.x;
  int cnt = gcursor[b]; if (cnt > BCAP) cnt = BCAP;
  const int base = bbase[b];
  const unsigned* tp = temp + (size_t)b * BCAP;

  if (tid < 256) { hist[tid] = 0; ofs[tid] = 0; }
  for (int i = tid; i < cnt; i += 1024) ebuf[i] = tp[i];
  __syncthreads();
  for (int i = tid; i < cnt; i += 1024) atomicAdd(&hist[(ebuf[i] >> 16) & 255], 1);
  __syncthreads();

  if (tid < 256) scn[tid] = hist[tid];
  __syncthreads();
  #pragma unroll
  for (int off = 1; off < 256; off <<= 1) {
    int x = 0;
    if (tid < 256 && tid >= off) x = scn[tid - off];
    __syncthreads();
    if (tid < 256) scn[tid] += x;
    __syncthreads();
  }
  if (tid < 256) {
    int v = hist[tid];
    int excl = scn[tid] - v;
    sexcl[tid] = excl;
    int node = (b << 8) + tid;
    if (node < n) {
      row_ptr[node] = base + excl;
      dinv[node] = rsqrtf((float)(v + 1));  // +1 self loop
    }
  }
  __syncthreads();

  for (int i = tid; i < cnt; i += 1024) {
    unsigned e = ebuf[i];
    int dl = (int)((e >> 16) & 255);
    int pos = sexcl[dl] + atomicAdd(&ofs[dl], 1);
    sorted[pos] = (unsigned short)(e & 0xFFFFu);
  }
  __syncthreads();
  for (int i = tid; i < cnt; i += 1024) csr16[base + i] = sorted[i];
}

// ---------------- Wt build + misc init (fused): Wt[n][k] = bf16(W[k][n]) ----------------
// blocks 0..255: transpose W; block 256: zero gcursor + zero xwp sentinel row n.

__global__ __launch_bounds__(256) void wt_init(const float* __restrict__ W,
                                               unsigned short* __restrict__ Wt,
                                               int* __restrict__ gcursor, int nbuck,
                                               unsigned* __restrict__ xwp_srow) {
  const int bk = (int)blockIdx.x;
  const int t  = (int)threadIdx.x;
  if (bk < 256) {
    Wt[t * FEATS + bk] = f2bf(W[bk * FEATS + t]);
  } else {
    if (t < nbuck) gcursor[t] = 0;
    if (t < 128) xwp_srow[t] = 0;  // 512 B sentinel row = 128 uints
  }
}

// ---------------- MFMA GEMM: xwp[r][:] = bf16( (x @ W)[r][:] * dinv[r] ) ----------------
// Block = 64 rows x 256 cols, 4 waves; B panel pinned in 128 VGPRs/wave; A
// converted cooperatively into pre-fragmented LDS; C staged through a
// XOR-swizzled 32 KB LDS tile and written as coalesced 512 B rows.

__global__ __launch_bounds__(256, 2) void gemm_mfma(const float* __restrict__ x,
                                                    const unsigned short* __restrict__ Wt,
                                                    const float* __restrict__ dinv,
                                                    unsigned short* __restrict__ xwp, int M) {
  __shared__ bf16x8 A_lds[32 * 64];            // 32 KB: [sub*8+kc][lane]
  __shared__ unsigned short C_lds[64 * 256];   // 32 KB: [row][swizzled col]
  const int wv   = (int)(threadIdx.x >> 6);
  const int lane = (int)(threadIdx.x & 63);
  const int lm   = lane & 15;
  const int quad = lane >> 4;
  const int m0   = (int)blockIdx.x * 64;

  bf16x8 Bfrag[4][8];
  #pragma unroll
  for (int ct = 0; ct < 4; ++ct) {
    const unsigned short* wrow = Wt + (size_t)(wv * 64 + ct * 16 + lm) * FEATS + quad * 8;
    #pragma unroll
    for (int kc = 0; kc < 8; ++kc)
      Bfrag[ct][kc] = *(const bf16x8*)(wrow + kc * 32);
  }

  {
    int arow = m0 + wv * 16 + lm; if (arow >= M) arow = M - 1;
    const float* xrow = x + (size_t)arow * FEATS + quad * 8;
    #pragma unroll
    for (int kc = 0; kc < 8; ++kc) {
      const float4 f0 = *(const float4*)(xrow + kc * 32);
      const float4 f1 = *(const float4*)(xrow + kc * 32 + 4);
      union { bf16x8 v; unsigned short u[8]; } a;
      a.u[0] = f2bf(f0.x); a.u[1] = f2bf(f0.y); a.u[2] = f2bf(f0.z); a.u[3] = f2bf(f0.w);
      a.u[4] = f2bf(f1.x); a.u[5] = f2bf(f1.y); a.u[6] = f2bf(f1.z); a.u[7] = f2bf(f1.w);
      A_lds[(wv * 8 + kc) * 64 + lane] = a.v;
    }
  }
  __syncthreads();

  #pragma unroll
  for (int sub = 0; sub < 4; ++sub) {
    bf16x8 Af[8];
    #pragma unroll
    for (int kc = 0; kc < 8; ++kc) Af[kc] = A_lds[(sub * 8 + kc) * 64 + lane];

    f32x4 acc[4];
    #pragma unroll
    for (int ct = 0; ct < 4; ++ct) acc[ct] = (f32x4){0.f, 0.f, 0.f, 0.f};

    #pragma unroll
    for (int kc = 0; kc < 8; ++kc) {
      #pragma unroll
      for (int ct = 0; ct < 4; ++ct)
        acc[ct] = __builtin_amdgcn_mfma_f32_16x16x32_bf16(Af[kc], Bfrag[ct][kc], acc[ct], 0, 0, 0);
    }

    #pragma unroll
    for (int r = 0; r < 4; ++r) {
      const int lrow = sub * 16 + quad * 4 + r;
      int grow = m0 + lrow; if (grow >= M) grow = M - 1;
      const float dd = dinv[grow];
      #pragma unroll
      for (int ct = 0; ct < 4; ++ct)
        C_lds[lrow * 256 + wv * 64 + ((ct ^ quad) << 4) + lm] = f2bf(acc[ct][r] * dd);
    }
  }
  __syncthreads();

  // coalesced writeout: 8 rounds x 8 rows; 32 threads/row x 16 B = 512 B/row.
  const int t  = (int)(threadIdx.x & 31);
  const int r8 = (int)(threadIdx.x >> 5);  // 0..7
  #pragma unroll
  for (int j = 0; j < 8; ++j) {
    const int lrow = j * 8 + r8;
    const int grow = m0 + lrow;
    if (grow < M) {
      const int qr = (lrow >> 2) & 3;
      const unsigned short* srcp = C_lds + lrow * 256 + (((t * 16) ^ (qr << 5)) >> 1);
      *(uint4*)(xwp + (size_t)grow * FEATS + t * 8) = *(const uint4*)srcp;
    }
  }
}

// ---------------- aggregation: paired-edge uint4 gathers ----------------
// Wave = 2 edges (half = lane>>5) x 32 lanes (cl = lane&31, 16 B each): one
// gather instruction moves TWO full 512 B rows. Sentinel row n (zeroed)
// absorbs tails; shfl_xor(32) fold merges the halves once per node.

#define AGG_ACC(J0, CNT) do {                                                      \
    uint4 vv[CNT];                                                                 \
    _Pragma("unroll")                                                              \
    for (int j = 0; j < (CNT); ++j) {                                              \
      int sj = __shfl(s, (J0) + 2 * j + half);                                     \
      vv[j] = *(const uint4*)(xb + ((size_t)sj << 8));                             \
    }                                                                              \
    _Pragma("unroll")                                                              \
    for (int j = 0; j < (CNT); ++j) {                                              \
      a0 += bflo(vv[j].x); a1 += bfhi(vv[j].x);                                    \
      a2 += bflo(vv[j].y); a3 += bfhi(vv[j].y);                                    \
      a4 += bflo(vv[j].z); a5 += bfhi(vv[j].z);                                    \
      a6 += bflo(vv[j].w); a7 += bfhi(vv[j].w);                                    \
    }                                                                              \
  } while (0)

__global__ __launch_bounds__(256) void aggregate(const unsigned short* __restrict__ xwp,
                                                 const float* __restrict__ dinv,
                                                 const int* __restrict__ row_ptr,
                                                 const unsigned short* __restrict__ csr16,
                                                 const float* __restrict__ bias,
                                                 float* __restrict__ out, int n) {
  const int node = (int)((blockIdx.x * blockDim.x + threadIdx.x) >> 6);
  const int lane = (int)(threadIdx.x & 63);
  if (node >= n) return;
  const int half = lane >> 5;                     // 0: even edges, 1: odd edges
  const int cl   = lane & 31;                     // 16 B column group
  const unsigned short* xb = xwp + cl * 8;        // + row*256 elems per gather

  float a0 = 0.f, a1 = 0.f, a2 = 0.f, a3 = 0.f, a4 = 0.f, a5 = 0.f, a6 = 0.f, a7 = 0.f;
  {  // self-loop row: accumulate in half 0 only (fold would double-count)
    uint4 v = *(const uint4*)(xb + ((size_t)node << 8));
    if (half == 0) {
      a0 = bflo(v.x); a1 = bfhi(v.x); a2 = bflo(v.y); a3 = bfhi(v.y);
      a4 = bflo(v.z); a5 = bfhi(v.z); a6 = bflo(v.w); a7 = bfhi(v.w);
    }
  }

  const int beg = row_ptr[node];
  const int end = row_ptr[node + 1];
  for (int base = beg; base < end; base += 64) {
    int idx = base + lane;
    int s = (idx < end) ? (int)csr16[idx] : n;    // sentinel -> zero row
    int m = end - base; if (m > 64) m = 64;
    int i = 0;
    for (; i + 16 <= m; i += 16) AGG_ACC(i, 8);   // 8 paired gathers, 16 edges
    if (i < m) {
      if (m - i <= 8) AGG_ACC(i, 4);              // short tail: 4 paired gathers
      else            AGG_ACC(i, 8);              // long tail, sentinel-padded
    }
  }

  // merge the two edge-halves
  a0 += __shfl_xor(a0, 32); a1 += __shfl_xor(a1, 32);
  a2 += __shfl_xor(a2, 32); a3 += __shfl_xor(a3, 32);
  a4 += __shfl_xor(a4, 32); a5 += __shfl_xor(a5, 32);
  a6 += __shfl_xor(a6, 32); a7 += __shfl_xor(a7, 32);

  // lane writes 4 floats at col cl*8 + half*4 (its own quarter of the row)
  const float s0 = half ? a4 : a0;
  const float s1 = half ? a5 : a1;
  const float s2 = half ? a6 : a2;
  const float s3 = half ? a7 : a3;
  const float dd = dinv[node];
  const float* bp = bias + cl * 8 + half * 4;
  f32x4 o;
  o.x = fmaxf(fmaf(s0, dd, bp[0]), 0.f);
  o.y = fmaxf(fmaf(s1, dd, bp[1]), 0.f);
  o.z = fmaxf(fmaf(s2, dd, bp[2]), 0.f);
  o.w = fmaxf(fmaf(s3, dd, bp[3]), 0.f);
  // NT store: 51 MB output, written once -- keep xwp in L2
  __builtin_nontemporal_store(o, (f32x4*)(out + (size_t)node * 256 + cl * 8 + half * 4));
}

// ---------------- launch ----------------

extern "C" void kernel_launch(void* const* d_in, const int* in_sizes, int n_in,
                              void* d_out, int out_size, void* d_ws, size_t ws_size,
                              hipStream_t stream) {
  const float* x  = (const float*)d_in[0];   // [n, 256]
  const int*   ei = (const int*)d_in[1];     // [2, E]
  const float* W  = (const float*)d_in[2];   // [256, 256]
  const float* b  = (const float*)d_in[3];   // [256]

  const int n = in_sizes[0] / FEATS;         // 50000
  const int E = in_sizes[1] / 2;             // 1,600,000
  const int* src = ei;
  const int* dst = ei + E;
  const int nbuck = (n + 255) >> 8;          // 196

  // workspace layout (bytes); xwp has n+1 rows (row n = zero sentinel)
  char* ws = (char*)d_ws;
  size_t o0 = 0;
  unsigned short* xwp    = (unsigned short*)(ws + o0); o0 += (size_t)(n + 1) * 512;
  unsigned short* Wt     = (unsigned short*)(ws + o0); o0 += 131072;
  float*          dinv   = (float*)(ws + o0);          o0 += 200064;
  int*            row_ptr = (int*)(ws + o0);           o0 += 200064;
  unsigned short* csr16  = (unsigned short*)(ws + o0); o0 += 3200000;
  int*            gcursor = (int*)(ws + o0);           o0 += 1024;
  int*            bbase   = (int*)(ws + o0);           o0 += 1024;
  unsigned*       temp    = (unsigned*)(ws + o0);      o0 += (size_t)MAXBUCK * BCAP * 4;
  // total ~37.4 MB

  // fused: W transpose (blocks 0-255) + gcursor zero + xwp sentinel row (block 256)
  hipLaunchKernelGGL(wt_init, dim3(257), dim3(256), 0, stream, W, Wt, gcursor, nbuck,
                     (unsigned*)(xwp + (size_t)n * 256));

  const int g_p1 = (E + 4095) / 4096;  // 391
  hipLaunchKernelGGL(pass1_bin, dim3(g_p1), dim3(1024), 0, stream, src, dst, E, nbuck, gcursor, temp);
  hipLaunchKernelGGL(scan_buckets, dim3(1), dim3(256), 0, stream, gcursor, bbase, row_ptr, nbuck, n);
  hipLaunchKernelGGL(pass2_csr, dim3(nbuck), dim3(1024), 0, stream, temp, gcursor, bbase,
                     csr16, row_ptr, dinv, n);

  hipLaunchKernelGGL(gemm_mfma, dim3((n + 63) / 64), dim3(256), 0, stream, x, Wt, dinv, xwp, n);

  const int g_agg = (n * 64 + 255) / 256;  // one wave per node
  hipLaunchKernelGGL(aggregate, dim3(g_agg), dim3(256), 0, stream,
                     xwp, dinv, row_ptr, csr16, b, (float*)d_out, n);
}